// Round 2
// baseline (226.249 us; speedup 1.0000x reference)
//
#include <hip/hip_runtime.h>
#include <hip/hip_bf16.h>

// NCF fused forward, persistent-block version.
// Block = 256 threads (4 waves), processes TILE=64 (user,item) pairs per iteration,
// grid-strides over 6400 tiles with register prefetch of the next tile's item rows.
// Phases per tile: regs->LDS store (+gmf partial dot), GEMM1(128x128),
// GEMM2(128x64), GEMM3(64x32), final dot+sigmoid.
// Weights pre-transposed to bf16 [out][in] in d_ws by ncf_prep.

typedef __attribute__((ext_vector_type(8))) short bf16x8;
typedef __attribute__((ext_vector_type(4))) float f32x4;

__device__ __forceinline__ short f2bf(float x){
  unsigned u = __float_as_uint(x);
  u += 0x7fffu + ((u >> 16) & 1u);
  return (short)(u >> 16);
}
__device__ __forceinline__ float bf2f(short s){
  return __uint_as_float(((unsigned)(unsigned short)s) << 16);
}

// ---- prep: W1[128,128],W2[128,64],W3[64,32] (stored [in][out]) -> bf16 [out][in] in ws ----
__global__ __launch_bounds__(256) void ncf_prep(
    const float* __restrict__ W1, const float* __restrict__ W2,
    const float* __restrict__ W3, short* __restrict__ ws)
{
  int i = blockIdx.x * 256 + threadIdx.x;
  if (i < 128*128){
    int j = i >> 7, k = i & 127;                 // W1T[j][k] = W1[k][j]
    ws[i] = f2bf(W1[k*128 + j]);
  } else if (i < 128*128 + 64*128){
    int t = i - 128*128; int j = t >> 7, k = t & 127;  // W2T[j][k] = W2[k][j]
    ws[i] = f2bf(W2[k*64 + j]);
  } else if (i < 128*128 + 64*128 + 32*64){
    int t = i - (128*128 + 64*128); int j = t >> 6, k = t & 63; // W3T[j][k] = W3[k][j]
    ws[i] = f2bf(W3[k*32 + j]);
  }
}

__global__ __launch_bounds__(256, 4) void ncf_main(
    const int* __restrict__ user, const int* __restrict__ item,
    const float* __restrict__ Wu_gmf, const float* __restrict__ bu_gmf,
    const float* __restrict__ Wu_mlp, const float* __restrict__ bu_mlp,
    const float* __restrict__ Wi_gmf, const float* __restrict__ bi_gmf,
    const float* __restrict__ Wi_mlp, const float* __restrict__ bi_mlp,
    const short* __restrict__ W1T, const float* __restrict__ b1,
    const short* __restrict__ W2T, const float* __restrict__ b2,
    const short* __restrict__ W3T, const float* __restrict__ b3,
    const float* __restrict__ Wp, const float* __restrict__ bp,
    float* __restrict__ out, int N, int total, int ntiles)
{
  __shared__ __align__(16) short s_inter[64][136];  // inter (bf16); reused as h2 (cols 0..63)
  __shared__ __align__(16) short s_h1[64][136];     // h1 (bf16)
  __shared__ __align__(16) short s_h3[64][36];      // h3 (bf16)
  __shared__           float s_pg[64];              // gmf . Wp[0:64] partial

  const int tid = threadIdx.x;
  const int r  = tid >> 2, q = tid & 3, e0 = q * 16;
  const int w  = tid >> 6, l = tid & 63;
  const int lr = l & 15,  lg = l >> 4;
  const int G  = gridDim.x;

  // prefetch registers: next tile's item rows (mlp + gmf), 16 elems each
  float4 im[4], ig[4];

  // ---------- prologue: issue item loads for first tile ----------
  {
    int p = blockIdx.x * 64 + r; if (p >= total) p = total - 1;
    long ib = (long)item[p] * 64;
    const float4* imp = (const float4*)(Wi_mlp + ib + e0);
    const float4* igp = (const float4*)(Wi_gmf + ib + e0);
    #pragma unroll
    for (int j = 0; j < 4; j++){ im[j] = imp[j]; ig[j] = igp[j]; }
  }

  for (int t = blockIdx.x; t < ntiles; t += G){
    const int p0 = t * 64;

    // ---------- store phase: regs -> LDS (bf16), gmf partial dot ----------
    {
      int p = p0 + r; if (p >= total) p = total - 1;
      int b = p / N;
      long ub = (long)user[b] * 64;
      const float4* ump  = (const float4*)(Wu_mlp + ub + e0);
      const float4* ugp  = (const float4*)(Wu_gmf + ub + e0);
      const float4* bump = (const float4*)(bu_mlp + e0);
      const float4* bimp = (const float4*)(bi_mlp + e0);
      const float4* bugp = (const float4*)(bu_gmf + e0);
      const float4* bigp = (const float4*)(bi_gmf + e0);
      const float4* wpp  = (const float4*)(Wp + e0);

      bf16x8 ua[2], ia[2];
      float pg = 0.f;
      #pragma unroll
      for (int j = 0; j < 4; j++){
        float4 um_ = ump[j], ub_ = bump[j];
        float4 ug_ = ugp[j], gb_ = bugp[j];
        float4 ibm = bimp[j], ibg = bigp[j];
        float4 wp_ = wpp[j];
        float a0 = um_.x + ub_.x, a1 = um_.y + ub_.y, a2 = um_.z + ub_.z, a3 = um_.w + ub_.w;
        float c0 = im[j].x + ibm.x, c1 = im[j].y + ibm.y, c2 = im[j].z + ibm.z, c3 = im[j].w + ibm.w;
        float u0 = ug_.x + gb_.x, u1 = ug_.y + gb_.y, u2 = ug_.z + gb_.z, u3 = ug_.w + gb_.w;
        float i0 = ig[j].x + ibg.x, i1 = ig[j].y + ibg.y, i2 = ig[j].z + ibg.z, i3 = ig[j].w + ibg.w;
        pg += u0*i0*wp_.x + u1*i1*wp_.y + u2*i2*wp_.z + u3*i3*wp_.w;
        int h = j >> 1, s = (j & 1) * 4;
        ua[h][s+0] = f2bf(a0); ua[h][s+1] = f2bf(a1); ua[h][s+2] = f2bf(a2); ua[h][s+3] = f2bf(a3);
        ia[h][s+0] = f2bf(c0); ia[h][s+1] = f2bf(c1); ia[h][s+2] = f2bf(c2); ia[h][s+3] = f2bf(c3);
      }
      *(bf16x8*)&s_inter[r][e0]          = ua[0];
      *(bf16x8*)&s_inter[r][e0 + 8]      = ua[1];
      *(bf16x8*)&s_inter[r][64 + e0]     = ia[0];
      *(bf16x8*)&s_inter[r][64 + e0 + 8] = ia[1];
      pg += __shfl_xor(pg, 1);
      pg += __shfl_xor(pg, 2);
      if (q == 0) s_pg[r] = pg;
    }
    __syncthreads();

    // ---------- prefetch next tile's item rows (in flight during GEMMs) ----------
    if (t + G < ntiles){
      int p = (t + G) * 64 + r;
      long ib = (long)item[p] * 64;
      const float4* imp = (const float4*)(Wi_mlp + ib + e0);
      const float4* igp = (const float4*)(Wi_gmf + ib + e0);
      #pragma unroll
      for (int j = 0; j < 4; j++){ im[j] = imp[j]; ig[j] = igp[j]; }
    }

    // ---------- GEMM1: h1[64x128] = relu(inter @ W1 + b1) ----------
    {
      f32x4 acc[4][2];
      #pragma unroll
      for (int mt = 0; mt < 4; mt++)
        #pragma unroll
        for (int nt = 0; nt < 2; nt++)
          acc[mt][nt] = (f32x4){0.f, 0.f, 0.f, 0.f};
      #pragma unroll
      for (int ks = 0; ks < 4; ks++){
        bf16x8 af[4];
        #pragma unroll
        for (int mt = 0; mt < 4; mt++)
          af[mt] = *(const bf16x8*)&s_inter[mt*16 + lr][ks*32 + lg*8];
        #pragma unroll
        for (int nt = 0; nt < 2; nt++){
          bf16x8 bfg = *(const bf16x8*)&W1T[(w*32 + nt*16 + lr)*128 + ks*32 + lg*8];
          #pragma unroll
          for (int mt = 0; mt < 4; mt++)
            acc[mt][nt] = __builtin_amdgcn_mfma_f32_16x16x32_bf16(af[mt], bfg, acc[mt][nt], 0, 0, 0);
        }
      }
      #pragma unroll
      for (int nt = 0; nt < 2; nt++){
        int col = w*32 + nt*16 + lr;
        float bb = b1[col];
        #pragma unroll
        for (int mt = 0; mt < 4; mt++)
          #pragma unroll
          for (int rr = 0; rr < 4; rr++){
            int row = mt*16 + lg*4 + rr;
            float v = acc[mt][nt][rr] + bb;
            s_h1[row][col] = f2bf(v > 0.f ? v : 0.f);
          }
      }
    }
    __syncthreads();

    // ---------- GEMM2: h2[64x64] = relu(h1 @ W2 + b2) -> s_inter cols 0..63 ----------
    {
      f32x4 acc2[4];
      #pragma unroll
      for (int mt = 0; mt < 4; mt++) acc2[mt] = (f32x4){0.f, 0.f, 0.f, 0.f};
      #pragma unroll
      for (int ks = 0; ks < 4; ks++){
        bf16x8 bfg = *(const bf16x8*)&W2T[(w*16 + lr)*128 + ks*32 + lg*8];
        #pragma unroll
        for (int mt = 0; mt < 4; mt++){
          bf16x8 a = *(const bf16x8*)&s_h1[mt*16 + lr][ks*32 + lg*8];
          acc2[mt] = __builtin_amdgcn_mfma_f32_16x16x32_bf16(a, bfg, acc2[mt], 0, 0, 0);
        }
      }
      int col = w*16 + lr;          // 0..63
      float bb = b2[col];
      #pragma unroll
      for (int mt = 0; mt < 4; mt++)
        #pragma unroll
        for (int rr = 0; rr < 4; rr++){
          int row = mt*16 + lg*4 + rr;
          float v = acc2[mt][rr] + bb;
          s_inter[row][col] = f2bf(v > 0.f ? v : 0.f);
        }
    }
    __syncthreads();

    // ---------- GEMM3: h3[64x32] = relu(h2 @ W3 + b3) (waves 0,1) ----------
    if (w < 2){
      f32x4 acc3[4];
      #pragma unroll
      for (int mt = 0; mt < 4; mt++) acc3[mt] = (f32x4){0.f, 0.f, 0.f, 0.f};
      #pragma unroll
      for (int ks = 0; ks < 2; ks++){
        bf16x8 bfg = *(const bf16x8*)&W3T[(w*16 + lr)*64 + ks*32 + lg*8];
        #pragma unroll
        for (int mt = 0; mt < 4; mt++){
          bf16x8 a = *(const bf16x8*)&s_inter[mt*16 + lr][ks*32 + lg*8];
          acc3[mt] = __builtin_amdgcn_mfma_f32_16x16x32_bf16(a, bfg, acc3[mt], 0, 0, 0);
        }
      }
      int col = w*16 + lr;          // 0..31
      float bb = b3[col];
      #pragma unroll
      for (int mt = 0; mt < 4; mt++)
        #pragma unroll
        for (int rr = 0; rr < 4; rr++){
          int row = mt*16 + lg*4 + rr;
          float v = acc3[mt][rr] + bb;
          s_h3[row][col] = f2bf(v > 0.f ? v : 0.f);
        }
    }
    __syncthreads();

    // ---------- final: out = sigmoid(s_pg + h3 . Wp[64:96] + bp) ----------
    {
      float sum = 0.f;
      #pragma unroll
      for (int i = 0; i < 8; i++){
        int c = q*8 + i;
        sum += bf2f(s_h3[r][c]) * Wp[64 + c];
      }
      sum += __shfl_xor(sum, 1);
      sum += __shfl_xor(sum, 2);
      if (q == 0 && p0 + r < total){
        float z = s_pg[r] + sum + bp[0];
        out[p0 + r] = 1.f / (1.f + __expf(-z));
      }
    }
    __syncthreads();   // protect s_pg/s_h3/s_inter before next tile's store phase
  }
}

extern "C" void kernel_launch(void* const* d_in, const int* in_sizes, int n_in,
                              void* d_out, int out_size, void* d_ws, size_t ws_size,
                              hipStream_t stream)
{
  const int*   user   = (const int*)  d_in[0];
  const int*   item   = (const int*)  d_in[1];
  const float* Wu_gmf = (const float*)d_in[3];
  const float* bu_gmf = (const float*)d_in[4];
  const float* Wu_mlp = (const float*)d_in[5];
  const float* bu_mlp = (const float*)d_in[6];
  const float* Wi_gmf = (const float*)d_in[7];
  const float* bi_gmf = (const float*)d_in[8];
  const float* Wi_mlp = (const float*)d_in[9];
  const float* bi_mlp = (const float*)d_in[10];
  const float* W1     = (const float*)d_in[11];
  const float* b1     = (const float*)d_in[12];
  const float* W2     = (const float*)d_in[13];
  const float* b2     = (const float*)d_in[14];
  const float* W3     = (const float*)d_in[15];
  const float* b3     = (const float*)d_in[16];
  const float* Wp     = (const float*)d_in[17];
  const float* bp     = (const float*)d_in[18];

  int B     = in_sizes[0];
  int total = in_sizes[1];          // B * N = 409600
  int N     = total / B;            // 100

  short* W1T = (short*)d_ws;                 // [128][128]
  short* W2T = W1T + 128*128;                // [64][128]
  short* W3T = W2T + 64*128;                 // [32][64]

  ncf_prep<<<104, 256, 0, stream>>>(W1, W2, W3, (short*)d_ws);

  int ntiles = (total + 63) / 64;
  int grid   = 1024;                         // 4 blocks/CU co-resident, persistent
  ncf_main<<<grid, 256, 0, stream>>>(user, item,
      Wu_gmf, bu_gmf, Wu_mlp, bu_mlp, Wi_gmf, bi_gmf, Wi_mlp, bi_mlp,
      W1T, b1, W2T, b2, W3T, b3, Wp, bp,
      (float*)d_out, N, total, ntiles);
}

// Round 3
// 85.919 us; speedup vs baseline: 2.6333x; 2.6333x over previous
//
#include <hip/hip_runtime.h>

// NCF fused forward, v3.
//  prep_w : transpose W1_item/W2/W3 to bf16 [out][in] in ws
//  prep_u : per batch-row b (4096): Xu[b][128] = (eu_m+bu_m)@W1_u + b1 + bi_mlp@W1_i (fp32)
//           wup[b][64] = (eu_g+bu_g) .* Wp[0:64];  cu[b] = wup[b] . bi_gmf
//  main   : per tile of 64 pairs: gather item rows only ->
//           GEMM1 K=64 (+Xu), GEMM2 K=128, GEMM3 K=64, final dot+sigmoid.

typedef __attribute__((ext_vector_type(8))) short bf16x8;
typedef __attribute__((ext_vector_type(4))) float f32x4;

__device__ __forceinline__ short f2bf(float x){
  unsigned u = __float_as_uint(x);
  u += 0x7fffu + ((u >> 16) & 1u);
  return (short)(u >> 16);
}
__device__ __forceinline__ float bf2f(short s){
  return __uint_as_float(((unsigned)(unsigned short)s) << 16);
}

// ---- prep_w: W1iT[128][64], W2T[64][128], W3T[32][64] (bf16, [out][in]) ----
__global__ __launch_bounds__(256) void ncf_prep_w(
    const float* __restrict__ W1, const float* __restrict__ W2,
    const float* __restrict__ W3, short* __restrict__ ws)
{
  int i = blockIdx.x * 256 + threadIdx.x;
  if (i < 8192){                      // W1iT[col][k] = W1[64+k][col]
    int col = i >> 6, k = i & 63;
    ws[i] = f2bf(W1[(64 + k)*128 + col]);
  } else if (i < 16384){              // W2T[col][k] = W2[k][col]
    int t = i - 8192; int col = t >> 7, k = t & 127;
    ws[i] = f2bf(W2[k*64 + col]);
  } else if (i < 18432){              // W3T[col][k] = W3[k][col]
    int t = i - 16384; int col = t >> 6, k = t & 63;
    ws[i] = f2bf(W3[k*32 + col]);
  }
}

// ---- prep_u: one block (128 thr) per batch row ----
__global__ __launch_bounds__(128) void ncf_prep_u(
    const int* __restrict__ user,
    const float* __restrict__ Wu_gmf, const float* __restrict__ bu_gmf,
    const float* __restrict__ Wu_mlp, const float* __restrict__ bu_mlp,
    const float* __restrict__ bi_gmf, const float* __restrict__ bi_mlp,
    const float* __restrict__ W1, const float* __restrict__ b1,
    const float* __restrict__ Wp,
    float* __restrict__ Xu, float* __restrict__ wup, float* __restrict__ cu,
    int B)
{
  int b = blockIdx.x; if (b >= B) return;
  int j = threadIdx.x;                   // 0..127
  long u = (long)user[b];
  float acc = b1[j];
  #pragma unroll 4
  for (int k = 0; k < 64; k++){
    float eu = Wu_mlp[u*64 + k] + bu_mlp[k];
    acc += eu * W1[k*128 + j] + bi_mlp[k] * W1[(64 + k)*128 + j];
  }
  Xu[b*128 + j] = acc;
  if (j < 64){                           // wave 0 only
    float wg = (Wu_gmf[u*64 + j] + bu_gmf[j]) * Wp[j];
    wup[b*64 + j] = wg;
    float c = wg * bi_gmf[j];
    c += __shfl_xor(c, 1);  c += __shfl_xor(c, 2);
    c += __shfl_xor(c, 4);  c += __shfl_xor(c, 8);
    c += __shfl_xor(c, 16); c += __shfl_xor(c, 32);
    if (j == 0) cu[b] = c;
  }
}

// ---- main: 64 pairs per block, 256 threads (4 waves) ----
__global__ __launch_bounds__(256) void ncf_main(
    const int* __restrict__ item,
    const float* __restrict__ Wi_mlp, const float* __restrict__ Wi_gmf,
    const short* __restrict__ W1iT, const short* __restrict__ W2T,
    const short* __restrict__ W3T,
    const float* __restrict__ b2, const float* __restrict__ b3,
    const float* __restrict__ Wp, const float* __restrict__ bp,
    const float* __restrict__ Xu, const float* __restrict__ wup,
    const float* __restrict__ cu,
    float* __restrict__ out, int N, int total)
{
  __shared__ __align__(16) short s_item[64][72];   // item mlp rows (bf16); reused as h2
  __shared__ __align__(16) short s_h1[64][136];    // h1 (bf16)
  __shared__ __align__(16) short s_h3[64][36];     // h3 (bf16)
  __shared__ int   s_bidx[64];
  __shared__ float s_pg[64];

  const int tid = threadIdx.x;
  const int p0  = blockIdx.x * 64;

  // ---------- gather: item rows only + gmf partial dot ----------
  {
    int r = tid >> 2, q = tid & 3;
    int p = p0 + r; if (p >= total) p = total - 1;
    int b = p / N;
    long ib = (long)item[p] * 64;
    const float4* imp = (const float4*)(Wi_mlp + ib) + q*4;
    const float4* igp = (const float4*)(Wi_gmf + ib) + q*4;
    const float4* wq  = (const float4*)(wup + (long)b*64) + q*4;
    bf16x8 ia[2];
    float pg = 0.f;
    #pragma unroll
    for (int j = 0; j < 4; j++){
      float4 v = imp[j];
      float4 g = igp[j];
      float4 wv = wq[j];
      pg += g.x*wv.x + g.y*wv.y + g.z*wv.z + g.w*wv.w;
      int h = j >> 1, s = (j & 1) * 4;
      ia[h][s+0] = f2bf(v.x); ia[h][s+1] = f2bf(v.y);
      ia[h][s+2] = f2bf(v.z); ia[h][s+3] = f2bf(v.w);
    }
    *(bf16x8*)&s_item[r][q*16]     = ia[0];
    *(bf16x8*)&s_item[r][q*16 + 8] = ia[1];
    pg += __shfl_xor(pg, 1);
    pg += __shfl_xor(pg, 2);
    if (q == 0){ s_bidx[r] = b; s_pg[r] = pg + cu[b]; }
  }
  __syncthreads();

  const int w  = tid >> 6, l = tid & 63;
  const int lr = l & 15,  lg = l >> 4;

  // ---------- GEMM1: h1[64x128] = relu(Xu[b] + item @ W1_i), K=64 ----------
  {
    f32x4 acc[4][2];
    #pragma unroll
    for (int mt = 0; mt < 4; mt++)
      #pragma unroll
      for (int nt = 0; nt < 2; nt++)
        acc[mt][nt] = (f32x4){0.f, 0.f, 0.f, 0.f};
    #pragma unroll
    for (int ks = 0; ks < 2; ks++){
      bf16x8 af[4];
      #pragma unroll
      for (int mt = 0; mt < 4; mt++)
        af[mt] = *(const bf16x8*)&s_item[mt*16 + lr][ks*32 + lg*8];
      #pragma unroll
      for (int nt = 0; nt < 2; nt++){
        bf16x8 bfg = *(const bf16x8*)&W1iT[(w*32 + nt*16 + lr)*64 + ks*32 + lg*8];
        #pragma unroll
        for (int mt = 0; mt < 4; mt++)
          acc[mt][nt] = __builtin_amdgcn_mfma_f32_16x16x32_bf16(af[mt], bfg, acc[mt][nt], 0, 0, 0);
      }
    }
    #pragma unroll
    for (int nt = 0; nt < 2; nt++){
      int col = w*32 + nt*16 + lr;
      #pragma unroll
      for (int mt = 0; mt < 4; mt++)
        #pragma unroll
        for (int rr = 0; rr < 4; rr++){
          int row = mt*16 + lg*4 + rr;
          float v = acc[mt][nt][rr] + Xu[s_bidx[row]*128 + col];
          s_h1[row][col] = f2bf(v > 0.f ? v : 0.f);
        }
    }
  }
  __syncthreads();

  // ---------- GEMM2: h2[64x64] = relu(h1 @ W2 + b2) -> s_item cols 0..63 ----------
  {
    f32x4 acc2[4];
    #pragma unroll
    for (int mt = 0; mt < 4; mt++) acc2[mt] = (f32x4){0.f, 0.f, 0.f, 0.f};
    #pragma unroll
    for (int ks = 0; ks < 4; ks++){
      bf16x8 bfg = *(const bf16x8*)&W2T[(w*16 + lr)*128 + ks*32 + lg*8];
      #pragma unroll
      for (int mt = 0; mt < 4; mt++){
        bf16x8 a = *(const bf16x8*)&s_h1[mt*16 + lr][ks*32 + lg*8];
        acc2[mt] = __builtin_amdgcn_mfma_f32_16x16x32_bf16(a, bfg, acc2[mt], 0, 0, 0);
      }
    }
    int col = w*16 + lr;               // 0..63
    float bb = b2[col];
    #pragma unroll
    for (int mt = 0; mt < 4; mt++)
      #pragma unroll
      for (int rr = 0; rr < 4; rr++){
        int row = mt*16 + lg*4 + rr;
        float v = acc2[mt][rr] + bb;
        s_item[row][col] = f2bf(v > 0.f ? v : 0.f);
      }
  }
  __syncthreads();

  // ---------- GEMM3: h3[64x32] = relu(h2 @ W3 + b3), K=64 (waves 0,1) ----------
  if (w < 2){
    f32x4 acc3[4];
    #pragma unroll
    for (int mt = 0; mt < 4; mt++) acc3[mt] = (f32x4){0.f, 0.f, 0.f, 0.f};
    #pragma unroll
    for (int ks = 0; ks < 2; ks++){
      bf16x8 bfg = *(const bf16x8*)&W3T[(w*16 + lr)*64 + ks*32 + lg*8];
      #pragma unroll
      for (int mt = 0; mt < 4; mt++){
        bf16x8 a = *(const bf16x8*)&s_item[mt*16 + lr][ks*32 + lg*8];
        acc3[mt] = __builtin_amdgcn_mfma_f32_16x16x32_bf16(a, bfg, acc3[mt], 0, 0, 0);
      }
    }
    int col = w*16 + lr;               // 0..31
    float bb = b3[col];
    #pragma unroll
    for (int mt = 0; mt < 4; mt++)
      #pragma unroll
      for (int rr = 0; rr < 4; rr++){
        int row = mt*16 + lg*4 + rr;
        float v = acc3[mt][rr] + bb;
        s_h3[row][col] = f2bf(v > 0.f ? v : 0.f);
      }
  }
  __syncthreads();

  // ---------- final: out = sigmoid(pg + h3 . Wp[64:96] + bp) ----------
  {
    int r = tid >> 2, q = tid & 3;
    float sum = 0.f;
    #pragma unroll
    for (int i = 0; i < 8; i++){
      int c = q*8 + i;
      sum += bf2f(s_h3[r][c]) * Wp[64 + c];
    }
    sum += __shfl_xor(sum, 1);
    sum += __shfl_xor(sum, 2);
    int p = p0 + r;
    if (q == 0 && p < total){
      float z = s_pg[r] + sum + bp[0];
      out[p] = 1.f / (1.f + __expf(-z));
    }
  }
}

extern "C" void kernel_launch(void* const* d_in, const int* in_sizes, int n_in,
                              void* d_out, int out_size, void* d_ws, size_t ws_size,
                              hipStream_t stream)
{
  const int*   user   = (const int*)  d_in[0];
  const int*   item   = (const int*)  d_in[1];
  const float* Wu_gmf = (const float*)d_in[3];
  const float* bu_gmf = (const float*)d_in[4];
  const float* Wu_mlp = (const float*)d_in[5];
  const float* bu_mlp = (const float*)d_in[6];
  const float* Wi_gmf = (const float*)d_in[7];
  const float* bi_gmf = (const float*)d_in[8];
  const float* Wi_mlp = (const float*)d_in[9];
  const float* bi_mlp = (const float*)d_in[10];
  const float* W1     = (const float*)d_in[11];
  const float* b1     = (const float*)d_in[12];
  const float* W2     = (const float*)d_in[13];
  const float* b2     = (const float*)d_in[14];
  const float* W3     = (const float*)d_in[15];
  const float* b3     = (const float*)d_in[16];
  const float* Wp     = (const float*)d_in[17];
  const float* bp     = (const float*)d_in[18];

  int B     = in_sizes[0];            // 4096
  int total = in_sizes[1];            // B * N = 409600
  int N     = total / B;              // 100

  // ws layout: [W1iT 16KB][W2T 16KB][W3T 4KB][pad -> 36864B][Xu B*128 f32][wup B*64 f32][cu B f32]
  short* W1iT = (short*)d_ws;
  short* W2T  = W1iT + 8192;
  short* W3T  = W2T  + 8192;
  float* Xu   = (float*)((char*)d_ws + 36864);
  float* wup  = Xu  + (size_t)B * 128;
  float* cuv  = wup + (size_t)B * 64;

  ncf_prep_w<<<72, 256, 0, stream>>>(W1, W2, W3, (short*)d_ws);
  ncf_prep_u<<<B, 128, 0, stream>>>(user, Wu_gmf, bu_gmf, Wu_mlp, bu_mlp,
                                    bi_gmf, bi_mlp, W1, b1, Wp,
                                    Xu, wup, cuv, B);

  int nblk = (total + 63) / 64;
  ncf_main<<<nblk, 256, 0, stream>>>(item, Wi_mlp, Wi_gmf,
      W1iT, W2T, W3T, b2, b3, Wp, bp, Xu, wup, cuv,
      (float*)d_out, N, total);
}

// Round 4
// 85.600 us; speedup vs baseline: 2.6431x; 1.0037x over previous
//
#include <hip/hip_runtime.h>

// NCF fused forward, v4 (persistent main + reg-hoisted weights + MFMA prep_u).
//  prep_w : W1uT/W1iT/W2T/W3T -> bf16 [out][in] in ws; c1 = b1 + bi_mlp@W1i
//  prep_u : 64 users/block MFMA GEMM: Xu[b] = (eu_m+bu_m)@W1u + c1 (f32)
//           wup[b] = (eu_g+bu_g).*Wp[0:64]; cu[b] = wup[b].bi_gmf
//  main   : persistent blocks, 64 pairs/tile: gather item rows ->
//           GEMM1 K=64 (+Xu from LDS), GEMM2 K=128, GEMM3 K=64, dot+sigmoid.

typedef __attribute__((ext_vector_type(8))) short bf16x8;
typedef __attribute__((ext_vector_type(4))) float f32x4;

__device__ __forceinline__ short f2bf(float x){
  unsigned u = __float_as_uint(x);
  u += 0x7fffu + ((u >> 16) & 1u);
  return (short)(u >> 16);
}
__device__ __forceinline__ float bf2f(short s){
  return __uint_as_float(((unsigned)(unsigned short)s) << 16);
}

// ws layout (bytes):
//   0      W1uT bf16 [128][64]
//   16384  W1iT bf16 [128][64]
//   32768  W2T  bf16 [64][128]
//   49152  W3T  bf16 [32][64]
//   53248  c1   f32  [128]
//   57344  Xu   f32  [B][128]
//   then   wup  f32  [B][64],  cu f32 [B]

__global__ __launch_bounds__(256) void ncf_prep_w(
    const float* __restrict__ W1, const float* __restrict__ W2,
    const float* __restrict__ W3, const float* __restrict__ b1,
    const float* __restrict__ bi_mlp, short* __restrict__ ws,
    float* __restrict__ c1)
{
  if (blockIdx.x == 104){                    // c1[j] = b1[j] + sum_k bi_mlp[k]*W1[64+k][j]
    int j = threadIdx.x;
    if (j < 128){
      float acc = b1[j];
      #pragma unroll 4
      for (int k = 0; k < 64; k++)
        acc += bi_mlp[k] * W1[(64 + k)*128 + j];
      c1[j] = acc;
    }
    return;
  }
  int i = blockIdx.x * 256 + threadIdx.x;
  if (i < 8192){                              // W1uT[col][k] = W1[k][col], k<64
    int col = i >> 6, k = i & 63;
    ws[i] = f2bf(W1[k*128 + col]);
  } else if (i < 16384){                      // W1iT[col][k] = W1[64+k][col]
    int t = i - 8192; int col = t >> 6, k = t & 63;
    ws[i] = f2bf(W1[(64 + k)*128 + col]);
  } else if (i < 24576){                      // W2T[col][k] = W2[k][col]
    int t = i - 16384; int col = t >> 7, k = t & 127;
    ws[i] = f2bf(W2[k*64 + col]);
  } else if (i < 26624){                      // W3T[col][k] = W3[k][col]
    int t = i - 24576; int col = t >> 6, k = t & 63;
    ws[i] = f2bf(W3[k*32 + col]);
  }
}

// ---- prep_u: 64 users per block, MFMA GEMM K=64 ----
__global__ __launch_bounds__(256) void ncf_prep_u(
    const int* __restrict__ user,
    const float* __restrict__ Wu_gmf, const float* __restrict__ bu_gmf,
    const float* __restrict__ Wu_mlp, const float* __restrict__ bu_mlp,
    const float* __restrict__ bi_gmf, const float* __restrict__ Wp,
    const short* __restrict__ W1uT, const float* __restrict__ c1,
    float* __restrict__ Xu, float* __restrict__ wup, float* __restrict__ cu)
{
  __shared__ __align__(16) short s_eu[64][72];
  const int tid = threadIdx.x;
  const int r = tid >> 2, q = tid & 3;
  const int b = blockIdx.x * 64 + r;
  long u = (long)user[b];

  {
    const float4* ump = (const float4*)(Wu_mlp + u*64) + q*4;
    const float4* bmp = (const float4*)(bu_mlp) + q*4;
    const float4* ugp = (const float4*)(Wu_gmf + u*64) + q*4;
    const float4* bgp = (const float4*)(bu_gmf) + q*4;
    const float4* wpp = (const float4*)(Wp) + q*4;
    const float4* bip = (const float4*)(bi_gmf) + q*4;
    float4* wdst = (float4*)(wup + (long)b*64) + q*4;
    bf16x8 ea[2];
    float cacc = 0.f;
    #pragma unroll
    for (int j = 0; j < 4; j++){
      float4 m = ump[j], mb = bmp[j];
      int h = j >> 1, s = (j & 1) * 4;
      ea[h][s+0] = f2bf(m.x + mb.x); ea[h][s+1] = f2bf(m.y + mb.y);
      ea[h][s+2] = f2bf(m.z + mb.z); ea[h][s+3] = f2bf(m.w + mb.w);
      float4 g = ugp[j], gb = bgp[j], wp = wpp[j], bi = bip[j];
      float4 wg; wg.x = (g.x+gb.x)*wp.x; wg.y = (g.y+gb.y)*wp.y;
                 wg.z = (g.z+gb.z)*wp.z; wg.w = (g.w+gb.w)*wp.w;
      wdst[j] = wg;
      cacc += wg.x*bi.x + wg.y*bi.y + wg.z*bi.z + wg.w*bi.w;
    }
    *(bf16x8*)&s_eu[r][q*16]     = ea[0];
    *(bf16x8*)&s_eu[r][q*16 + 8] = ea[1];
    cacc += __shfl_xor(cacc, 1);
    cacc += __shfl_xor(cacc, 2);
    if (q == 0) cu[b] = cacc;
  }
  __syncthreads();

  const int w = tid >> 6, l = tid & 63, lr = l & 15, lg = l >> 4;
  f32x4 acc[4][2];
  #pragma unroll
  for (int mt = 0; mt < 4; mt++)
    #pragma unroll
    for (int nt = 0; nt < 2; nt++)
      acc[mt][nt] = (f32x4){0.f, 0.f, 0.f, 0.f};
  #pragma unroll
  for (int ks = 0; ks < 2; ks++){
    bf16x8 af[4];
    #pragma unroll
    for (int mt = 0; mt < 4; mt++)
      af[mt] = *(const bf16x8*)&s_eu[mt*16 + lr][ks*32 + lg*8];
    #pragma unroll
    for (int nt = 0; nt < 2; nt++){
      bf16x8 bf_ = *(const bf16x8*)&W1uT[(w*32 + nt*16 + lr)*64 + ks*32 + lg*8];
      #pragma unroll
      for (int mt = 0; mt < 4; mt++)
        acc[mt][nt] = __builtin_amdgcn_mfma_f32_16x16x32_bf16(af[mt], bf_, acc[mt][nt], 0, 0, 0);
    }
  }
  #pragma unroll
  for (int nt = 0; nt < 2; nt++){
    int col = w*32 + nt*16 + lr;
    float cc = c1[col];
    #pragma unroll
    for (int mt = 0; mt < 4; mt++)
      #pragma unroll
      for (int rr = 0; rr < 4; rr++){
        int row = mt*16 + lg*4 + rr;
        Xu[(long)(blockIdx.x*64 + row)*128 + col] = acc[mt][nt][rr] + cc;
      }
  }
}

// ---- main: persistent, 64 pairs per tile ----
__global__ __launch_bounds__(256) void ncf_main(
    const int* __restrict__ item,
    const float* __restrict__ Wi_mlp, const float* __restrict__ Wi_gmf,
    const short* __restrict__ W1iT, const short* __restrict__ W2T,
    const short* __restrict__ W3T,
    const float* __restrict__ b2, const float* __restrict__ b3,
    const float* __restrict__ Wp, const float* __restrict__ bp,
    const float* __restrict__ Xu, const float* __restrict__ wup,
    const float* __restrict__ cu,
    float* __restrict__ out, int N, int total, int ntiles, int Bsz)
{
  __shared__ __align__(16) short s_item[64][72];   // item mlp rows; reused as h2
  __shared__ __align__(16) short s_h1[64][136];
  __shared__ __align__(16) short s_h3[64][34];
  __shared__ __align__(16) float s_xu[2][128];
  __shared__           float s_pg[64];

  const int tid = threadIdx.x;
  const int r  = tid >> 2, q = tid & 3;
  const int w  = tid >> 6, l = tid & 63;
  const int lr = l & 15,  lg = l >> 4;
  const int G  = gridDim.x;

  // ---- weights -> registers, once per block ----
  bf16x8 w1f[2][2], w2f[4], w3f[2];
  #pragma unroll
  for (int nt = 0; nt < 2; nt++)
    #pragma unroll
    for (int ks = 0; ks < 2; ks++)
      w1f[nt][ks] = *(const bf16x8*)&W1iT[(w*32 + nt*16 + lr)*64 + ks*32 + lg*8];
  #pragma unroll
  for (int ks = 0; ks < 4; ks++)
    w2f[ks] = *(const bf16x8*)&W2T[(w*16 + lr)*128 + ks*32 + lg*8];
  #pragma unroll
  for (int ks = 0; ks < 2; ks++)
    w3f[ks] = *(const bf16x8*)&W3T[((w&1)*16 + lr)*64 + ks*32 + lg*8];

  for (int t = blockIdx.x; t < ntiles; t += G){
    const int p0  = t * 64;
    const int b0  = p0 / N;
    const int thr = (b0 + 1) * N;

    // ---- gather: item rows -> LDS(bf16); gmf partial dot; Xu rows -> LDS ----
    {
      int p = p0 + r;
      int bl = (p >= thr) ? 1 : 0;
      int b  = b0 + bl;
      long ib = (long)item[p] * 64;
      const float4* imp = (const float4*)(Wi_mlp + ib) + q*4;
      const float4* igp = (const float4*)(Wi_gmf + ib) + q*4;
      const float4* wq  = (const float4*)(wup + (long)b*64) + q*4;
      bf16x8 ia[2];
      float pg = 0.f;
      #pragma unroll
      for (int j = 0; j < 4; j++){
        float4 v = imp[j];
        float4 g = igp[j];
        float4 wv = wq[j];
        pg += g.x*wv.x + g.y*wv.y + g.z*wv.z + g.w*wv.w;
        int h = j >> 1, s = (j & 1) * 4;
        ia[h][s+0] = f2bf(v.x); ia[h][s+1] = f2bf(v.y);
        ia[h][s+2] = f2bf(v.z); ia[h][s+3] = f2bf(v.w);
      }
      *(bf16x8*)&s_item[r][q*16]     = ia[0];
      *(bf16x8*)&s_item[r][q*16 + 8] = ia[1];
      pg += __shfl_xor(pg, 1);
      pg += __shfl_xor(pg, 2);
      if (q == 0) s_pg[r] = pg + cu[b];
      // stage the <=2 distinct Xu rows
      int i2 = tid >> 7, col = tid & 127;
      int bb = b0 + i2; if (bb >= Bsz) bb = Bsz - 1;
      s_xu[i2][col] = Xu[(long)bb*128 + col];
    }
    __syncthreads();

    // ---- GEMM1: h1 = relu(item @ W1i + Xu[b]), K=64 ----
    {
      f32x4 acc[4][2];
      #pragma unroll
      for (int mt = 0; mt < 4; mt++)
        #pragma unroll
        for (int nt = 0; nt < 2; nt++)
          acc[mt][nt] = (f32x4){0.f, 0.f, 0.f, 0.f};
      #pragma unroll
      for (int ks = 0; ks < 2; ks++){
        bf16x8 af[4];
        #pragma unroll
        for (int mt = 0; mt < 4; mt++)
          af[mt] = *(const bf16x8*)&s_item[mt*16 + lr][ks*32 + lg*8];
        #pragma unroll
        for (int nt = 0; nt < 2; nt++)
          #pragma unroll
          for (int mt = 0; mt < 4; mt++)
            acc[mt][nt] = __builtin_amdgcn_mfma_f32_16x16x32_bf16(af[mt], w1f[nt][ks], acc[mt][nt], 0, 0, 0);
      }
      #pragma unroll
      for (int nt = 0; nt < 2; nt++){
        int col = w*32 + nt*16 + lr;
        #pragma unroll
        for (int mt = 0; mt < 4; mt++)
          #pragma unroll
          for (int rr = 0; rr < 4; rr++){
            int row = mt*16 + lg*4 + rr;
            int bl = (p0 + row >= thr) ? 1 : 0;
            float v = acc[mt][nt][rr] + s_xu[bl][col];
            s_h1[row][col] = f2bf(v > 0.f ? v : 0.f);
          }
      }
    }
    __syncthreads();

    // ---- GEMM2: h2 = relu(h1 @ W2 + b2) -> s_item cols 0..63 ----
    {
      f32x4 acc2[4];
      #pragma unroll
      for (int mt = 0; mt < 4; mt++) acc2[mt] = (f32x4){0.f, 0.f, 0.f, 0.f};
      #pragma unroll
      for (int ks = 0; ks < 4; ks++)
        #pragma unroll
        for (int mt = 0; mt < 4; mt++){
          bf16x8 a = *(const bf16x8*)&s_h1[mt*16 + lr][ks*32 + lg*8];
          acc2[mt] = __builtin_amdgcn_mfma_f32_16x16x32_bf16(a, w2f[ks], acc2[mt], 0, 0, 0);
        }
      int col = w*16 + lr;
      float bb = b2[col];
      #pragma unroll
      for (int mt = 0; mt < 4; mt++)
        #pragma unroll
        for (int rr = 0; rr < 4; rr++){
          int row = mt*16 + lg*4 + rr;
          float v = acc2[mt][rr] + bb;
          s_item[row][col] = f2bf(v > 0.f ? v : 0.f);
        }
    }
    __syncthreads();

    // ---- GEMM3: h3 = relu(h2 @ W3 + b3), waves 0,1 ----
    if (w < 2){
      f32x4 acc3[4];
      #pragma unroll
      for (int mt = 0; mt < 4; mt++) acc3[mt] = (f32x4){0.f, 0.f, 0.f, 0.f};
      #pragma unroll
      for (int ks = 0; ks < 2; ks++)
        #pragma unroll
        for (int mt = 0; mt < 4; mt++){
          bf16x8 a = *(const bf16x8*)&s_item[mt*16 + lr][ks*32 + lg*8];
          acc3[mt] = __builtin_amdgcn_mfma_f32_16x16x32_bf16(a, w3f[ks], acc3[mt], 0, 0, 0);
        }
      int col = w*16 + lr;
      float bb = b3[col];
      #pragma unroll
      for (int mt = 0; mt < 4; mt++)
        #pragma unroll
        for (int rr = 0; rr < 4; rr++){
          int row = mt*16 + lg*4 + rr;
          float v = acc3[mt][rr] + bb;
          s_h3[row][col] = f2bf(v > 0.f ? v : 0.f);
        }
    }
    __syncthreads();

    // ---- final: out = sigmoid(pg + h3 . Wp[64:96] + bp) ----
    {
      float sum = 0.f;
      #pragma unroll
      for (int i = 0; i < 8; i++){
        int c = q*8 + i;
        sum += bf2f(s_h3[r][c]) * Wp[64 + c];
      }
      sum += __shfl_xor(sum, 1);
      sum += __shfl_xor(sum, 2);
      int p = p0 + r;
      if (q == 0 && p < total){
        float z = s_pg[r] + sum + bp[0];
        out[p] = 1.f / (1.f + __expf(-z));
      }
    }
    __syncthreads();   // protect LDS before next tile's gather
  }
}

extern "C" void kernel_launch(void* const* d_in, const int* in_sizes, int n_in,
                              void* d_out, int out_size, void* d_ws, size_t ws_size,
                              hipStream_t stream)
{
  const int*   user   = (const int*)  d_in[0];
  const int*   item   = (const int*)  d_in[1];
  const float* Wu_gmf = (const float*)d_in[3];
  const float* bu_gmf = (const float*)d_in[4];
  const float* Wu_mlp = (const float*)d_in[5];
  const float* bu_mlp = (const float*)d_in[6];
  const float* Wi_gmf = (const float*)d_in[7];
  const float* bi_gmf = (const float*)d_in[8];
  const float* Wi_mlp = (const float*)d_in[9];
  const float* bi_mlp = (const float*)d_in[10];
  const float* W1     = (const float*)d_in[11];
  const float* b1     = (const float*)d_in[12];
  const float* W2     = (const float*)d_in[13];
  const float* b2     = (const float*)d_in[14];
  const float* W3     = (const float*)d_in[15];
  const float* b3     = (const float*)d_in[16];
  const float* Wp     = (const float*)d_in[17];
  const float* bp     = (const float*)d_in[18];

  int B     = in_sizes[0];            // 4096
  int total = in_sizes[1];            // 409600
  int N     = total / B;              // 100

  char* wsb = (char*)d_ws;
  short* W1uT = (short*)wsb;                     // 8192
  short* W1iT = (short*)(wsb + 16384);           // 8192
  short* W2T  = (short*)(wsb + 32768);           // 8192
  short* W3T  = (short*)(wsb + 49152);           // 2048
  float* c1   = (float*)(wsb + 53248);           // 128
  float* Xu   = (float*)(wsb + 57344);           // B*128
  float* wup  = Xu  + (size_t)B * 128;           // B*64
  float* cuv  = wup + (size_t)B * 64;            // B

  ncf_prep_w<<<105, 256, 0, stream>>>(W1, W2, W3, b1, bi_mlp, (short*)d_ws, c1);
  ncf_prep_u<<<B/64, 256, 0, stream>>>(user, Wu_gmf, bu_gmf, Wu_mlp, bu_mlp,
                                       bi_gmf, Wp, W1uT, c1, Xu, wup, cuv);

  int ntiles = (total + 63) / 64;
  ncf_main<<<1024, 256, 0, stream>>>(item, Wi_mlp, Wi_gmf,
      W1iT, W2T, W3T, b2, b3, Wp, bp, Xu, wup, cuv,
      (float*)d_out, N, total, ntiles, B);
}